// Round 1
// baseline (50.786 us; speedup 1.0000x reference)
//
#include <hip/hip_runtime.h>

// Problem constants (fixed by the reference):
//   hidden_layers: (4, B, T, D) float32
//   word_ids:      (B, T) int32, SORTED along T, values in [0, W] (W = NONE)
//   output:        (B*(W+1), D) float32; row (b,0)=CLS mean-over-layers of
//                  token 0; row (b,1+w)=segment mean of layer-mean over
//                  tokens with word_ids[b,t]==w (0 if empty segment).
#define NB 32
#define NT 512
#define ND 1024
#define NW 100
#define NL 4

__global__ __launch_bounds__(256) void bert_word_pool_kernel(
    const float* __restrict__ hidden,   // (NL, NB, NT, ND)
    const int*   __restrict__ word_ids, // (NB, NT)
    float*       __restrict__ out)      // (NB*(NW+1), ND)
{
    const int row = blockIdx.x;          // 0 .. NB*(NW+1)-1
    const int b   = row / (NW + 1);
    const int j   = row - b * (NW + 1);  // 0 = cls, 1..NW = word (j-1)
    const int d0  = threadIdx.x * 4;     // 256 threads * 4 floats = 1024

    const size_t layer_stride = (size_t)NB * NT * ND;
    const float* hb = hidden + (size_t)b * NT * ND;

    float4 acc = make_float4(0.f, 0.f, 0.f, 0.f);
    float scale;

    if (j == 0) {
        // CLS: mean over layers of token 0
        #pragma unroll
        for (int l = 0; l < NL; ++l) {
            const float4 v = *reinterpret_cast<const float4*>(hb + (size_t)l * layer_stride + d0);
            acc.x += v.x; acc.y += v.y; acc.z += v.z; acc.w += v.w;
        }
        scale = 1.0f / (float)NL;
    } else {
        const int w = j - 1;
        const int* ids = word_ids + b * NT;

        // lower_bound(w): first t with ids[t] >= w
        int lo = 0, hi = NT;
        while (lo < hi) {
            int mid = (lo + hi) >> 1;
            if (ids[mid] < w) lo = mid + 1; else hi = mid;
        }
        const int start = lo;
        // lower_bound(w+1): one past last t with ids[t] == w
        hi = NT;
        while (lo < hi) {
            int mid = (lo + hi) >> 1;
            if (ids[mid] < w + 1) lo = mid + 1; else hi = mid;
        }
        const int end   = lo;
        const int count = end - start;

        for (int t = start; t < end; ++t) {
            const float* hp = hb + (size_t)t * ND + d0;
            #pragma unroll
            for (int l = 0; l < NL; ++l) {
                const float4 v = *reinterpret_cast<const float4*>(hp + (size_t)l * layer_stride);
                acc.x += v.x; acc.y += v.y; acc.z += v.z; acc.w += v.w;
            }
        }
        scale = (count > 0) ? (1.0f / (float)(NL * count)) : 0.0f;
    }

    float4 r = make_float4(acc.x * scale, acc.y * scale, acc.z * scale, acc.w * scale);
    *reinterpret_cast<float4*>(out + (size_t)row * ND + d0) = r;
}

extern "C" void kernel_launch(void* const* d_in, const int* in_sizes, int n_in,
                              void* d_out, int out_size, void* d_ws, size_t ws_size,
                              hipStream_t stream) {
    const float* hidden   = (const float*)d_in[0];
    const int*   word_ids = (const int*)d_in[1];
    // d_in[2] = num_words scalar (==100), compiled in as NW.
    float* out = (float*)d_out;

    const int rows = NB * (NW + 1);   // 3232 blocks
    bert_word_pool_kernel<<<rows, 256, 0, stream>>>(hidden, word_ids, out);
}